// Round 9
// baseline (254.232 us; speedup 1.0000x reference)
//
#include <hip/hip_runtime.h>
#include <stdint.h>

typedef __bf16 bf16x8 __attribute__((ext_vector_type(8)));
typedef float f32x4 __attribute__((ext_vector_type(4)));
typedef int i32x4 __attribute__((ext_vector_type(4)));
typedef unsigned short u16;

#define DEVI static __device__ __forceinline__

// f32 -> bf16 (RNE)
DEVI u16 bfu(float f){
  unsigned u = __builtin_bit_cast(unsigned, f);
  unsigned r = u + 0x7fffu + ((u >> 16) & 1u);
  return (u16)(r >> 16);
}
DEVI float ubf(u16 h){
  unsigned u = ((unsigned)h) << 16;
  return __builtin_bit_cast(float, u);
}
DEVI unsigned packbf(float a, float b){
  return (unsigned)bfu(a) | ((unsigned)bfu(b) << 16);
}

// async global->LDS, 16B/lane; LDS dest = wave-uniform base + lane*16
DEVI void gload16(const void* g, void* s){
  __builtin_amdgcn_global_load_lds(
      (const __attribute__((address_space(1))) unsigned int*)g,
      (__attribute__((address_space(3))) unsigned int*)s, 16, 0, 0);
}

DEVI float waveReduceMax(float v){
  for (int off = 1; off < 64; off <<= 1) v = fmaxf(v, __shfl_xor(v, off));
  return v;
}

DEVI float blockReduceMax(float v, float* sred){
  for (int off = 32; off; off >>= 1) v = fmaxf(v, __shfl_xor(v, off));
  int w = threadIdx.x >> 6;
  if ((threadIdx.x & 63) == 0) sred[w] = v;
  __syncthreads();
  float r = fmaxf(fmaxf(sred[0], sred[1]), fmaxf(sred[2], sred[3]));
  __syncthreads();
  return r;
}

// ---------------- bodies ----------------
// one wave handles one 1024-row: amax -> scale -> int8 + bf16 copies. No LDS/barriers.
DEVI void quant_row_wave(const float* __restrict__ in, int8_t* __restrict__ qo,
                         u16* __restrict__ bo, float* __restrict__ so, int row){
  const int lane = threadIdx.x & 63;
  const float* rp = in + (size_t)row * 1024;
  float4 v[4];
  float am = 0.f;
  for (int i = 0; i < 4; i++){
    v[i] = *(const float4*)(rp + i * 256 + lane * 4);
    am = fmaxf(am, fmaxf(fmaxf(fabsf(v[i].x), fabsf(v[i].y)),
                         fmaxf(fabsf(v[i].z), fabsf(v[i].w))));
  }
  am = waveReduceMax(am);
  const float s = fmaxf(am, 1e-5f) / 127.0f;
  if (lane == 0) so[row] = s;
  for (int i = 0; i < 4; i++){
    char4 q;
    q.x = (int8_t)(int)fminf(fmaxf(rintf(v[i].x / s), -128.f), 127.f);
    q.y = (int8_t)(int)fminf(fmaxf(rintf(v[i].y / s), -128.f), 127.f);
    q.z = (int8_t)(int)fminf(fmaxf(rintf(v[i].z / s), -128.f), 127.f);
    q.w = (int8_t)(int)fminf(fmaxf(rintf(v[i].w / s), -128.f), 127.f);
    *(char4*)(qo + (size_t)row * 1024 + i * 256 + lane * 4) = q;
    ushort4 h; h.x = bfu(v[i].x); h.y = bfu(v[i].y); h.z = bfu(v[i].z); h.w = bfu(v[i].w);
    *(ushort4*)(bo + (size_t)row * 1024 + i * 256 + lane * 4) = h;
  }
}

DEVI void quant_b_body(const float* __restrict__ b, float* __restrict__ qb, float* sred){
  const int t = threadIdx.x;
  float am = 0.f;
  for (int i = t; i < 3072; i += 256) am = fmaxf(am, fabsf(b[i]));
  am = blockReduceMax(am, sred);
  const float s = fmaxf(am, 1e-5f) / 127.0f;
  for (int i = t; i < 3072; i += 256){
    float q = fminf(fmaxf(rintf(b[i] / s), -128.f), 127.f);
    qb[i] = q * s;
  }
}

DEVI void topk_lin_body(int idx, const float* __restrict__ x, const float* __restrict__ Wq,
                        const float* __restrict__ bq, float* __restrict__ tlin){
  const int o = idx & 2047, bn = idx >> 11;
  const int b_ = bn / 17, n = bn % 17;
  const float* xr = x + ((size_t)b_ * 1024 + n) * 1024;
  const float* wr = Wq + (size_t)o * 1024;
  const float4* x4 = (const float4*)xr;
  const float4* w4 = (const float4*)wr;
  float s = 0.f;
  for (int c = 0; c < 64; c++){
    float4 a = x4[c], b = w4[c];
    s += a.x * b.x + a.y * b.y + a.z * b.z + a.w * b.w;
  }
  s += xr[256] * wr[256];
  tlin[idx] = s + bq[o];
}

// i8 GEMM, BK=64, linear LDS, bf16 output (R6 interior)
DEVI void gemm_i8_body(char* smem, int tid, const int8_t* __restrict__ A, const int8_t* __restrict__ Bm,
    const float* __restrict__ sx, const float* __restrict__ sw, const float* __restrict__ qb,
    u16* __restrict__ out){
  int8_t* As = (int8_t*)smem;
  int8_t* Bs = (int8_t*)(smem + 8192);
  const int t = threadIdx.x, l = t & 63, w = t >> 6;
  const int m0 = (tid / 24) * 128, n0 = (tid % 24) * 128;
  const int wm = (w >> 1) * 64, wn = (w & 1) * 64, lr = l & 15, lg = l >> 4;
  i32x4 acc[4][4];
  i32x4 z = {0, 0, 0, 0};
  for (int i = 0; i < 4; i++) for (int j = 0; j < 4; j++) acc[i][j] = z;
  for (int kt = 0; kt < 16; kt++){
    __syncthreads();
    for (int it = 0; it < 2; it++){
      int c = w * 2 + it;
      int idx = c * 64 + l;
      int r = idx >> 2, boff = (idx & 3) * 16;
      gload16(A  + (size_t)(m0 + r) * 1024 + kt * 64 + boff, &As[c * 1024]);
      gload16(Bm + (size_t)(n0 + r) * 1024 + kt * 64 + boff, &Bs[c * 1024]);
    }
    __syncthreads();
    i32x4 a[4], b[4];
    for (int i = 0; i < 4; i++) a[i] = *(const i32x4*)(&As[(wm + i * 16 + lr) * 64 + lg * 16]);
    for (int j = 0; j < 4; j++) b[j] = *(const i32x4*)(&Bs[(wn + j * 16 + lr) * 64 + lg * 16]);
    __builtin_amdgcn_s_setprio(1);
    for (int i = 0; i < 4; i++)
      for (int j = 0; j < 4; j++)
        acc[i][j] = __builtin_amdgcn_mfma_i32_16x16x64_i8(a[i], b[j], acc[i][j], 0, 0, 0);
    __builtin_amdgcn_s_setprio(0);
  }
  for (int i = 0; i < 4; i++){
    int row = m0 + wm + i * 16 + lg * 4;
    for (int j = 0; j < 4; j++){
      int col = n0 + wn + j * 16 + lr;
      float swc = sw[col], qbc = qb[col];
      for (int r = 0; r < 4; r++)
        out[(size_t)(row + r) * 3072 + col] = bfu((float)acc[i][j][r] * sx[row + r] * swc + qbc);
    }
  }
}

// bf16 GEMM, BK=32, linear LDS (R6 interior). MODE 0: QKV scatter+bias; MODE 1: proj f32 out
template<int MODE>
DEVI void gemm_bf16_body(char* smem, int tid, const u16* __restrict__ A, const u16* __restrict__ Bm,
    const float* __restrict__ bias, void* __restrict__ outp, int K, int N, int nxb){
  u16* As = (u16*)smem;
  u16* Bs = (u16*)(smem + 8192);
  const int t = threadIdx.x, l = t & 63, w = t >> 6;
  const int m0 = (tid / nxb) * 128, n0 = (tid % nxb) * 128;
  const int wm = (w >> 1) * 64, wn = (w & 1) * 64, lr = l & 15, lg = l >> 4;
  f32x4 acc[4][4];
  f32x4 z = {0.f, 0.f, 0.f, 0.f};
  for (int i = 0; i < 4; i++) for (int j = 0; j < 4; j++) acc[i][j] = z;
  const int nkt = K >> 5;
  for (int kt = 0; kt < nkt; kt++){
    __syncthreads();
    for (int it = 0; it < 2; it++){
      int c = w * 2 + it;
      int idx = c * 64 + l;
      int r = idx >> 2, off = (idx & 3) * 8;
      gload16(A  + (size_t)(m0 + r) * K + kt * 32 + off, &As[c * 512]);
      gload16(Bm + (size_t)(n0 + r) * K + kt * 32 + off, &Bs[c * 512]);
    }
    __syncthreads();
    bf16x8 a[4], b[4];
    for (int i = 0; i < 4; i++) a[i] = *(const bf16x8*)(&As[(wm + i * 16 + lr) * 32 + lg * 8]);
    for (int j = 0; j < 4; j++) b[j] = *(const bf16x8*)(&Bs[(wn + j * 16 + lr) * 32 + lg * 8]);
    __builtin_amdgcn_s_setprio(1);
    for (int i = 0; i < 4; i++)
      for (int j = 0; j < 4; j++)
        acc[i][j] = __builtin_amdgcn_mfma_f32_16x16x32_bf16(a[i], b[j], acc[i][j], 0, 0, 0);
    __builtin_amdgcn_s_setprio(0);
  }
  for (int i = 0; i < 4; i++){
    int row = m0 + wm + i * 16 + lg * 4;
    for (int j = 0; j < 4; j++){
      int col = n0 + wn + j * 16 + lr;
      float bc = bias[col];
      for (int r = 0; r < 4; r++){
        float v = acc[i][j][r] + bc;
        if (MODE == 0){
          int s = col >> 10, h = (col >> 6) & 15, d = col & 63;
          int b_ = (row + r) >> 10, n = (row + r) & 1023;
          ((u16*)outp)[(((size_t)(s * 64 + b_ * 16 + h)) * 1024 + n) * 64 + d] = bfu(v);
        } else {
          ((float*)outp)[(size_t)(row + r) * N + col] = v;
        }
      }
    }
  }
}

DEVI void topk_attn_body(int b2, const float* __restrict__ tlin, float* __restrict__ outp){
  const int idx = b2 * 256 + threadIdx.x;
  if (idx >= 4 * 16 * 17 * 17) return;
  const int mm = idx % 17; int rest = idx / 17;
  const int nn = rest % 17; rest /= 17;
  const int h = rest % 16; const int b_ = rest / 16;
  const float* tq = tlin + ((size_t)(b_ * 17 + nn)) * 2048 + h * 64;
  const float* tk = tlin + ((size_t)(b_ * 17 + mm)) * 2048 + 1024 + h * 64;
  float s = 0.f;
  for (int d = 0; d < 64; d++) s += tq[d] * tk[d];
  outp[71303168 + idx] = s * 0.125f;
}

// one wave handles one 3072-col q_lin row: amax -> scale -> iq/ik int8 (first 2048 cols)
DEVI void qlin_quant_wave(int row, const u16* __restrict__ qlin,
                          float* __restrict__ s_ql, int8_t* __restrict__ iq, int8_t* __restrict__ ik){
  const int lane = threadIdx.x & 63;
  const u16* rp = qlin + (size_t)row * 3072;
  uint4 raw[6];
  float am = 0.f;
  for (int i = 0; i < 6; i++){
    raw[i] = *(const uint4*)(rp + i * 512 + lane * 8);
    const u16* pp = (const u16*)&raw[i];
    for (int j = 0; j < 8; j++) am = fmaxf(am, fabsf(ubf(pp[j])));
  }
  am = waveReduceMax(am);
  const float s = fmaxf(am, 1e-5f) / 127.0f;
  if (lane == 0) s_ql[row] = s;
  const int b_ = row >> 10, n = row & 1023;
  for (int i = 0; i < 4; i++){
    const int o0 = i * 512 + lane * 8;
    int8_t* dst = (o0 < 1024) ? iq : ik;
    const int oo = o0 & 1023, h = oo >> 6, d = oo & 63;
    const size_t base = (((size_t)(b_ * 16 + h) * 1024 + n) * 64 + d);
    const u16* pp = (const u16*)&raw[i];
    union { int8_t c[8]; unsigned long long u; } pk;
    for (int j = 0; j < 8; j++)
      pk.c[j] = (int8_t)(int)fminf(fmaxf(rintf(ubf(pp[j]) / s), -128.f), 127.f);
    *(unsigned long long*)(dst + base) = pk.u;
  }
}

// flash attention, KVBLK=64: half the barriers/softmax updates of the 32-step version.
// V^T in dbuf LDS [2][64 d][72 pad]; P-repack shuffle scheme applied per-32-kv half.
DEVI void attn_body(u16* vt, int qt, int bz, const u16* __restrict__ qkv, u16* __restrict__ aout){
  const int t = threadIdx.x, l = t & 63, w = t >> 6, lr = l & 15, lg = l >> 4;
  const int b_ = bz >> 4, h = bz & 15;
  const u16* Q  = qkv + (size_t)bz * 65536;
  const u16* Kg = qkv + (size_t)(64 + bz) * 65536;
  const u16* Vg = qkv + (size_t)(128 + bz) * 65536;
  const int q0 = qt * 64 + w * 16;
  const bf16x8 bq0 = *(const bf16x8*)(Q + (size_t)(q0 + lr) * 64 + lg * 8);
  const bf16x8 bq1 = *(const bf16x8*)(Q + (size_t)(q0 + lr) * 64 + 32 + lg * 8);
  float m = -1e30f, lsum = 0.f;
  f32x4 o[4];
  f32x4 zf = {0.f, 0.f, 0.f, 0.f};
  for (int dt = 0; dt < 4; dt++) o[dt] = zf;
  const int hi = lg & 1, tt = lg >> 1;
  const int srcA = lr + 32 * hi, srcB = srcA + 16;
  const int vr = t & 63, dbase = (t >> 6) * 16;   // V stager: kv-row vr, 16 d-elems at dbase
  {
    uint4 v0 = *(const uint4*)(Vg + (size_t)vr * 64 + dbase);
    uint4 v1 = *(const uint4*)(Vg + (size_t)vr * 64 + dbase + 8);
    const u16* p0 = (const u16*)&v0; const u16* p1 = (const u16*)&v1;
    for (int j = 0; j < 8; j++){
      vt[(dbase + j) * 72 + vr] = p0[j];
      vt[(dbase + 8 + j) * 72 + vr] = p1[j];
    }
  }
  __syncthreads();
  int cur = 0;
  for (int kv0 = 0; kv0 < 1024; kv0 += 64){
    bf16x8 ak[4][2];
    for (int x = 0; x < 4; x++){
      ak[x][0] = *(const bf16x8*)(Kg + (size_t)(kv0 + x * 16 + lr) * 64 + lg * 8);
      ak[x][1] = *(const bf16x8*)(Kg + (size_t)(kv0 + x * 16 + lr) * 64 + 32 + lg * 8);
    }
    const bool more = (kv0 + 64) < 1024;
    uint4 vn0 = {0,0,0,0}, vn1 = {0,0,0,0};
    if (more){
      vn0 = *(const uint4*)(Vg + (size_t)(kv0 + 64 + vr) * 64 + dbase);
      vn1 = *(const uint4*)(Vg + (size_t)(kv0 + 64 + vr) * 64 + dbase + 8);
    }
    f32x4 st[4];
    __builtin_amdgcn_s_setprio(1);
    for (int x = 0; x < 4; x++){
      f32x4 c = zf;
      c = __builtin_amdgcn_mfma_f32_16x16x32_bf16(ak[x][0], bq0, c, 0, 0, 0);
      c = __builtin_amdgcn_mfma_f32_16x16x32_bf16(ak[x][1], bq1, c, 0, 0, 0);
      st[x] = c;
    }
    __builtin_amdgcn_s_setprio(0);
    float tmax = -1e30f;
    for (int x = 0; x < 4; x++)
      for (int r = 0; r < 4; r++){ st[x][r] *= 0.125f; tmax = fmaxf(tmax, st[x][r]); }
    tmax = fmaxf(tmax, __shfl_xor(tmax, 16));
    tmax = fmaxf(tmax, __shfl_xor(tmax, 32));
    if (__any(tmax > m)){                       // bit-exact skip: f==1 when no growth
      const float mn = fmaxf(m, tmax);
      const float f = __expf(m - mn);
      m = mn;
      lsum *= f;
      for (int dt = 0; dt < 4; dt++) for (int r = 0; r < 4; r++) o[dt][r] *= f;
    }
    float p[4][4], psum = 0.f;
    for (int x = 0; x < 4; x++)
      for (int r = 0; r < 4; r++){ float e = __expf(st[x][r] - m); p[x][r] = e; psum += e; }
    psum += __shfl_xor(psum, 16);
    psum += __shfl_xor(psum, 32);
    lsum += psum;
    // repack P^T -> B-frag layout, independently per 32-kv half
    int pk00 = (int)packbf(p[0][0], p[0][1]), pk01 = (int)packbf(p[0][2], p[0][3]);
    int pk10 = (int)packbf(p[1][0], p[1][1]), pk11 = (int)packbf(p[1][2], p[1][3]);
    int pk20 = (int)packbf(p[2][0], p[2][1]), pk21 = (int)packbf(p[2][2], p[2][3]);
    int pk30 = (int)packbf(p[3][0], p[3][1]), pk31 = (int)packbf(p[3][2], p[3][3]);
    int a0 = __shfl(pk00, srcA), a1 = __shfl(pk10, srcA);
    int b0 = __shfl(pk01, srcA), b1 = __shfl(pk11, srcA);
    int c0 = __shfl(pk00, srcB), c1 = __shfl(pk10, srcB);
    int d0 = __shfl(pk01, srcB), d1 = __shfl(pk11, srcB);
    int e0 = __shfl(pk20, srcA), e1 = __shfl(pk30, srcA);
    int f0 = __shfl(pk21, srcA), f1 = __shfl(pk31, srcA);
    int g0 = __shfl(pk20, srcB), g1 = __shfl(pk30, srcB);
    int h0 = __shfl(pk21, srcB), h1 = __shfl(pk31, srcB);
    union { unsigned u[4]; bf16x8 v; } bp0, bp1;
    bp0.u[0] = (unsigned)(tt ? a1 : a0);
    bp0.u[1] = (unsigned)(tt ? b1 : b0);
    bp0.u[2] = (unsigned)(tt ? c1 : c0);
    bp0.u[3] = (unsigned)(tt ? d1 : d0);
    bp1.u[0] = (unsigned)(tt ? e1 : e0);
    bp1.u[1] = (unsigned)(tt ? f1 : f0);
    bp1.u[2] = (unsigned)(tt ? g1 : g0);
    bp1.u[3] = (unsigned)(tt ? h1 : h0);
    __builtin_amdgcn_s_setprio(1);
    for (int dt = 0; dt < 4; dt++){
      bf16x8 av0 = *(const bf16x8*)(&vt[(cur * 64 + dt * 16 + lr) * 72 + lg * 8]);
      o[dt] = __builtin_amdgcn_mfma_f32_16x16x32_bf16(av0, bp0.v, o[dt], 0, 0, 0);
      bf16x8 av1 = *(const bf16x8*)(&vt[(cur * 64 + dt * 16 + lr) * 72 + 32 + lg * 8]);
      o[dt] = __builtin_amdgcn_mfma_f32_16x16x32_bf16(av1, bp1.v, o[dt], 0, 0, 0);
    }
    __builtin_amdgcn_s_setprio(0);
    if (more){
      const u16* p0 = (const u16*)&vn0; const u16* p1 = (const u16*)&vn1;
      const int nb = (cur ^ 1) * 64;
      for (int j = 0; j < 8; j++){
        vt[(nb + dbase + j) * 72 + vr] = p0[j];
        vt[(nb + dbase + 8 + j) * 72 + vr] = p1[j];
      }
    }
    __syncthreads();
    cur ^= 1;
  }
  const float rn = 1.0f / lsum;
  for (int dt = 0; dt < 4; dt++){
    ushort4 hv;
    hv.x = bfu(o[dt][0] * rn); hv.y = bfu(o[dt][1] * rn);
    hv.z = bfu(o[dt][2] * rn); hv.w = bfu(o[dt][3] * rn);
    *(ushort4*)(aout + ((size_t)(b_ * 1024 + q0 + lr)) * 1024 + h * 64 + dt * 16 + lg * 4) = hv;
  }
}

DEVI void qattn_body(int b2, const int8_t* __restrict__ iq, const int8_t* __restrict__ ik,
    const float* __restrict__ s_ql, float* __restrict__ outp){
  const int t = threadIdx.x, l = t & 63, w = t >> 6, lr = l & 15, lg = l >> 4;
  const int n0 = (b2 & 7) * 128, m0 = ((b2 >> 3) & 7) * 128, bz = b2 >> 6;
  const int wm = (w >> 1) * 64, wn = (w & 1) * 64;
  const int b_ = bz >> 4;
  const int8_t* Aq = iq + (size_t)bz * 65536;
  const int8_t* Bk = ik + (size_t)bz * 65536;
  i32x4 a[4], b[4];
  for (int i = 0; i < 4; i++) a[i] = *(const i32x4*)(Aq + (size_t)(m0 + wm + i * 16 + lr) * 64 + lg * 16);
  for (int j = 0; j < 4; j++) b[j] = *(const i32x4*)(Bk + (size_t)(n0 + wn + j * 16 + lr) * 64 + lg * 16);
  float* op = outp + 4194304 + (size_t)bz * 1048576;
  i32x4 z = {0, 0, 0, 0};
  for (int i = 0; i < 4; i++){
    int row = m0 + wm + i * 16 + lg * 4;
    for (int j = 0; j < 4; j++){
      i32x4 acc = __builtin_amdgcn_mfma_i32_16x16x64_i8(a[i], b[j], z, 0, 0, 0);
      int col = n0 + wn + j * 16 + lr;
      float sc = s_ql[b_ * 1024 + col] * 0.125f;
      for (int r = 0; r < 4; r++)
        op[(size_t)(row + r) * 1024 + col] = (float)acc[r] * s_ql[b_ * 1024 + row + r] * sc;
    }
  }
}

// ---------------- stage kernels ----------------
// layout: [0,544) topk_lin | [544,1568) quant x | [1568,2336) quant W | [2336,2848) Wp cast | 2848 quant_b
__global__ __launch_bounds__(256) void stageA(
    const float* __restrict__ x, const float* __restrict__ Wq, const float* __restrict__ bq,
    const float* __restrict__ Wp,
    int8_t* __restrict__ ix, u16* __restrict__ xb, float* __restrict__ sx,
    int8_t* __restrict__ iw, u16* __restrict__ wb, float* __restrict__ sw,
    float* __restrict__ qbv, u16* __restrict__ Wpb, float* __restrict__ tlin){
  __shared__ float sred[4];
  const int bid = blockIdx.x, t = threadIdx.x, wv = t >> 6;
  if (bid < 544){
    topk_lin_body(bid * 256 + t, x, Wq, bq, tlin);
  } else if (bid < 1568){
    quant_row_wave(x, ix, xb, sx, (bid - 544) * 4 + wv);
  } else if (bid < 2336){
    quant_row_wave(Wq, iw, wb, sw, (bid - 1568) * 4 + wv);
  } else if (bid < 2848){
    const int i = ((bid - 2336) * 256 + t) * 8;
    float4 a = *(const float4*)(Wp + i);
    float4 b = *(const float4*)(Wp + i + 4);
    ushort4 h0; h0.x = bfu(a.x); h0.y = bfu(a.y); h0.z = bfu(a.z); h0.w = bfu(a.w);
    ushort4 h1; h1.x = bfu(b.x); h1.y = bfu(b.y); h1.z = bfu(b.z); h1.w = bfu(b.w);
    *(ushort4*)(Wpb + i) = h0;
    *(ushort4*)(Wpb + i + 4) = h1;
  } else {
    quant_b_body(bq, qbv, sred);
  }
}

// layout: [0,768) bf16 QKV tiles (longer blocks first) | [768,1536) i8 tiles
__global__ __launch_bounds__(256) void stageB(
    const int8_t* __restrict__ ix, const int8_t* __restrict__ iw, const float* __restrict__ sx,
    const float* __restrict__ sw, const float* __restrict__ qbv, u16* __restrict__ qlin,
    const u16* __restrict__ xb, const u16* __restrict__ wb, const float* __restrict__ bq,
    u16* __restrict__ qkv){
  __shared__ __align__(16) char smem[16384];
  const int bid = blockIdx.x;
  if (bid < 768){
    const int tid = (bid & 7) * 96 + (bid >> 3);           // XCD-chunked
    gemm_bf16_body<0>(smem, tid, xb, wb, bq, qkv, 1024, 3072, 24);
  } else {
    const int g = bid - 768;
    const int tid = (g & 7) * 96 + (g >> 3);
    gemm_i8_body(smem, tid, ix, iw, sx, sw, qbv, qlin);
  }
}

// layout: [0,1024) attn | [1024,2048) qlin_quant (wave-per-row) | [2048,2121) topk_attn
__global__ __launch_bounds__(256) void stageC(
    const u16* __restrict__ qkv, u16* __restrict__ aout,
    const u16* __restrict__ qlin, float* __restrict__ sql,
    int8_t* __restrict__ iq, int8_t* __restrict__ ik,
    const float* __restrict__ tlin, float* __restrict__ dout){
  __shared__ __align__(16) char smem[18432];
  const int bid = blockIdx.x, wv = threadIdx.x >> 6;
  if (bid < 1024){
    const int wk = (bid & 7) * 128 + (bid >> 3);           // 8 bz per XCD chunk
    attn_body((u16*)smem, wk & 15, wk >> 4, qkv, aout);
  } else if (bid < 2048){
    qlin_quant_wave((bid - 1024) * 4 + wv, qlin, sql, iq, ik);
  } else {
    topk_attn_body(bid - 2048, tlin, dout);
  }
}

__global__ __launch_bounds__(256) void stageD(
    const u16* __restrict__ aout, const u16* __restrict__ Wpb, const float* __restrict__ bp,
    float* __restrict__ dout,
    const int8_t* __restrict__ iq, const int8_t* __restrict__ ik, const float* __restrict__ sql){
  __shared__ __align__(16) char smem[16384];
  const int bid = blockIdx.x;
  if (bid < 256) gemm_bf16_body<1>(smem, bid, aout, Wpb, bp, dout, 1024, 1024, 8);
  else {
    const int g = bid - 256;
    const int w = (g & 7) * 512 + (g >> 3);                // 8 bz per XCD chunk
    qattn_body(w, iq, ik, sql, dout);
  }
}

// ---------------- launcher ----------------
extern "C" void kernel_launch(void* const* d_in, const int* in_sizes, int n_in,
                              void* d_out, int out_size, void* d_ws, size_t ws_size,
                              hipStream_t stream){
  const float* x  = (const float*)d_in[0];
  const float* Wq = (const float*)d_in[1];
  const float* bq = (const float*)d_in[2];
  const float* Wp = (const float*)d_in[3];
  const float* bp = (const float*)d_in[4];
  char* ws = (char*)d_ws;
  size_t off = 0;
  auto alloc = [&](size_t bytes) -> void* {
    void* p = ws + off; off += (bytes + 255) & ~(size_t)255; return p;
  };
  u16*    qlin = (u16*)   alloc(4096ull * 3072 * 2);   // bf16
  int8_t* ix   = (int8_t*)alloc(4096ull * 1024);
  int8_t* iw   = (int8_t*)alloc(3072ull * 1024);
  int8_t* iq   = (int8_t*)alloc(64ull * 1024 * 64);
  int8_t* ik   = (int8_t*)alloc(64ull * 1024 * 64);
  u16*    xb   = (u16*)   alloc(4096ull * 1024 * 2);
  u16*    Wb   = (u16*)   alloc(3072ull * 1024 * 2);
  u16*    qkv  = (u16*)   alloc(3ull * 64 * 1024 * 64 * 2);
  u16*    aout = (u16*)   alloc(4096ull * 1024 * 2);
  u16*    Wpb  = (u16*)   alloc(1024ull * 1024 * 2);
  float*  tlin = (float*) alloc(4ull * 17 * 2048 * 4);
  float*  sx   = (float*) alloc(4096 * 4);
  float*  sw   = (float*) alloc(3072 * 4);
  float*  qbv  = (float*) alloc(3072 * 4);
  float*  sql  = (float*) alloc(4096 * 4);
  float*  dout = (float*)d_out;

  stageA<<<2849, 256, 0, stream>>>(x, Wq, bq, Wp, ix, xb, sx, iw, Wb, sw, qbv, Wpb, tlin);
  stageB<<<1536, 256, 0, stream>>>(ix, iw, sx, sw, qbv, qlin, xb, Wb, bq, qkv);
  stageC<<<2121, 256, 0, stream>>>(qkv, aout, qlin, sql, iq, ik, tlin, dout);
  stageD<<<4352, 256, 0, stream>>>(aout, Wpb, bp, dout, iq, ik, sql);
}

// Round 10
// 241.623 us; speedup vs baseline: 1.0522x; 1.0522x over previous
//
#include <hip/hip_runtime.h>
#include <stdint.h>

typedef __bf16 bf16x8 __attribute__((ext_vector_type(8)));
typedef float f32x4 __attribute__((ext_vector_type(4)));
typedef int i32x4 __attribute__((ext_vector_type(4)));
typedef unsigned short u16;

#define DEVI static __device__ __forceinline__

// f32 -> bf16 (RNE)
DEVI u16 bfu(float f){
  unsigned u = __builtin_bit_cast(unsigned, f);
  unsigned r = u + 0x7fffu + ((u >> 16) & 1u);
  return (u16)(r >> 16);
}
DEVI float ubf(u16 h){
  unsigned u = ((unsigned)h) << 16;
  return __builtin_bit_cast(float, u);
}
DEVI unsigned packbf(float a, float b){
  return (unsigned)bfu(a) | ((unsigned)bfu(b) << 16);
}

// async global->LDS, 16B/lane; LDS dest = wave-uniform base + lane*16
DEVI void gload16(const void* g, void* s){
  __builtin_amdgcn_global_load_lds(
      (const __attribute__((address_space(1))) unsigned int*)g,
      (__attribute__((address_space(3))) unsigned int*)s, 16, 0, 0);
}

DEVI float waveReduceMax(float v){
  for (int off = 1; off < 64; off <<= 1) v = fmaxf(v, __shfl_xor(v, off));
  return v;
}

DEVI float blockReduceMax(float v, float* sred){
  for (int off = 32; off; off >>= 1) v = fmaxf(v, __shfl_xor(v, off));
  int w = threadIdx.x >> 6;
  if ((threadIdx.x & 63) == 0) sred[w] = v;
  __syncthreads();
  float r = fmaxf(fmaxf(sred[0], sred[1]), fmaxf(sred[2], sred[3]));
  __syncthreads();
  return r;
}

// ---------------- bodies ----------------
// one wave handles one 1024-row: amax -> scale -> int8 + bf16 copies. No LDS/barriers.
DEVI void quant_row_wave(const float* __restrict__ in, int8_t* __restrict__ qo,
                         u16* __restrict__ bo, float* __restrict__ so, int row){
  const int lane = threadIdx.x & 63;
  const float* rp = in + (size_t)row * 1024;
  float4 v[4];
  float am = 0.f;
  for (int i = 0; i < 4; i++){
    v[i] = *(const float4*)(rp + i * 256 + lane * 4);
    am = fmaxf(am, fmaxf(fmaxf(fabsf(v[i].x), fabsf(v[i].y)),
                         fmaxf(fabsf(v[i].z), fabsf(v[i].w))));
  }
  am = waveReduceMax(am);
  const float s = fmaxf(am, 1e-5f) / 127.0f;
  if (lane == 0) so[row] = s;
  for (int i = 0; i < 4; i++){
    char4 q;
    q.x = (int8_t)(int)fminf(fmaxf(rintf(v[i].x / s), -128.f), 127.f);
    q.y = (int8_t)(int)fminf(fmaxf(rintf(v[i].y / s), -128.f), 127.f);
    q.z = (int8_t)(int)fminf(fmaxf(rintf(v[i].z / s), -128.f), 127.f);
    q.w = (int8_t)(int)fminf(fmaxf(rintf(v[i].w / s), -128.f), 127.f);
    *(char4*)(qo + (size_t)row * 1024 + i * 256 + lane * 4) = q;
    ushort4 h; h.x = bfu(v[i].x); h.y = bfu(v[i].y); h.z = bfu(v[i].z); h.w = bfu(v[i].w);
    *(ushort4*)(bo + (size_t)row * 1024 + i * 256 + lane * 4) = h;
  }
}

DEVI void quant_b_body(const float* __restrict__ b, float* __restrict__ qb, float* sred){
  const int t = threadIdx.x;
  float am = 0.f;
  for (int i = t; i < 3072; i += 256) am = fmaxf(am, fabsf(b[i]));
  am = blockReduceMax(am, sred);
  const float s = fmaxf(am, 1e-5f) / 127.0f;
  for (int i = t; i < 3072; i += 256){
    float q = fminf(fmaxf(rintf(b[i] / s), -128.f), 127.f);
    qb[i] = q * s;
  }
}

DEVI void topk_lin_body(int idx, const float* __restrict__ x, const float* __restrict__ Wq,
                        const float* __restrict__ bq, float* __restrict__ tlin){
  const int o = idx & 2047, bn = idx >> 11;
  const int b_ = bn / 17, n = bn % 17;
  const float* xr = x + ((size_t)b_ * 1024 + n) * 1024;
  const float* wr = Wq + (size_t)o * 1024;
  const float4* x4 = (const float4*)xr;
  const float4* w4 = (const float4*)wr;
  float s = 0.f;
  for (int c = 0; c < 64; c++){
    float4 a = x4[c], b = w4[c];
    s += a.x * b.x + a.y * b.y + a.z * b.z + a.w * b.w;
  }
  s += xr[256] * wr[256];
  tlin[idx] = s + bq[o];
}

// i8 GEMM, BK=64, linear LDS, bf16 output
DEVI void gemm_i8_body(char* smem, int tid, const int8_t* __restrict__ A, const int8_t* __restrict__ Bm,
    const float* __restrict__ sx, const float* __restrict__ sw, const float* __restrict__ qb,
    u16* __restrict__ out){
  int8_t* As = (int8_t*)smem;
  int8_t* Bs = (int8_t*)(smem + 8192);
  const int t = threadIdx.x, l = t & 63, w = t >> 6;
  const int m0 = (tid / 24) * 128, n0 = (tid % 24) * 128;
  const int wm = (w >> 1) * 64, wn = (w & 1) * 64, lr = l & 15, lg = l >> 4;
  i32x4 acc[4][4];
  i32x4 z = {0, 0, 0, 0};
  for (int i = 0; i < 4; i++) for (int j = 0; j < 4; j++) acc[i][j] = z;
  for (int kt = 0; kt < 16; kt++){
    __syncthreads();
    for (int it = 0; it < 2; it++){
      int c = w * 2 + it;
      int idx = c * 64 + l;
      int r = idx >> 2, boff = (idx & 3) * 16;
      gload16(A  + (size_t)(m0 + r) * 1024 + kt * 64 + boff, &As[c * 1024]);
      gload16(Bm + (size_t)(n0 + r) * 1024 + kt * 64 + boff, &Bs[c * 1024]);
    }
    __syncthreads();
    i32x4 a[4], b[4];
    for (int i = 0; i < 4; i++) a[i] = *(const i32x4*)(&As[(wm + i * 16 + lr) * 64 + lg * 16]);
    for (int j = 0; j < 4; j++) b[j] = *(const i32x4*)(&Bs[(wn + j * 16 + lr) * 64 + lg * 16]);
    __builtin_amdgcn_s_setprio(1);
    for (int i = 0; i < 4; i++)
      for (int j = 0; j < 4; j++)
        acc[i][j] = __builtin_amdgcn_mfma_i32_16x16x64_i8(a[i], b[j], acc[i][j], 0, 0, 0);
    __builtin_amdgcn_s_setprio(0);
  }
  for (int i = 0; i < 4; i++){
    int row = m0 + wm + i * 16 + lg * 4;
    for (int j = 0; j < 4; j++){
      int col = n0 + wn + j * 16 + lr;
      float swc = sw[col], qbc = qb[col];
      for (int r = 0; r < 4; r++)
        out[(size_t)(row + r) * 3072 + col] = bfu((float)acc[i][j][r] * sx[row + r] * swc + qbc);
    }
  }
}

// bf16 GEMM, BK=32, linear LDS. MODE 0: QKV scatter+bias; MODE 1: proj f32 out
template<int MODE>
DEVI void gemm_bf16_body(char* smem, int tid, const u16* __restrict__ A, const u16* __restrict__ Bm,
    const float* __restrict__ bias, void* __restrict__ outp, int K, int N, int nxb){
  u16* As = (u16*)smem;
  u16* Bs = (u16*)(smem + 8192);
  const int t = threadIdx.x, l = t & 63, w = t >> 6;
  const int m0 = (tid / nxb) * 128, n0 = (tid % nxb) * 128;
  const int wm = (w >> 1) * 64, wn = (w & 1) * 64, lr = l & 15, lg = l >> 4;
  f32x4 acc[4][4];
  f32x4 z = {0.f, 0.f, 0.f, 0.f};
  for (int i = 0; i < 4; i++) for (int j = 0; j < 4; j++) acc[i][j] = z;
  const int nkt = K >> 5;
  for (int kt = 0; kt < nkt; kt++){
    __syncthreads();
    for (int it = 0; it < 2; it++){
      int c = w * 2 + it;
      int idx = c * 64 + l;
      int r = idx >> 2, off = (idx & 3) * 8;
      gload16(A  + (size_t)(m0 + r) * K + kt * 32 + off, &As[c * 512]);
      gload16(Bm + (size_t)(n0 + r) * K + kt * 32 + off, &Bs[c * 512]);
    }
    __syncthreads();
    bf16x8 a[4], b[4];
    for (int i = 0; i < 4; i++) a[i] = *(const bf16x8*)(&As[(wm + i * 16 + lr) * 32 + lg * 8]);
    for (int j = 0; j < 4; j++) b[j] = *(const bf16x8*)(&Bs[(wn + j * 16 + lr) * 32 + lg * 8]);
    __builtin_amdgcn_s_setprio(1);
    for (int i = 0; i < 4; i++)
      for (int j = 0; j < 4; j++)
        acc[i][j] = __builtin_amdgcn_mfma_f32_16x16x32_bf16(a[i], b[j], acc[i][j], 0, 0, 0);
    __builtin_amdgcn_s_setprio(0);
  }
  for (int i = 0; i < 4; i++){
    int row = m0 + wm + i * 16 + lg * 4;
    for (int j = 0; j < 4; j++){
      int col = n0 + wn + j * 16 + lr;
      float bc = bias[col];
      for (int r = 0; r < 4; r++){
        float v = acc[i][j][r] + bc;
        if (MODE == 0){
          int s = col >> 10, h = (col >> 6) & 15, d = col & 63;
          int b_ = (row + r) >> 10, n = (row + r) & 1023;
          ((u16*)outp)[(((size_t)(s * 64 + b_ * 16 + h)) * 1024 + n) * 64 + d] = bfu(v);
        } else {
          ((float*)outp)[(size_t)(row + r) * N + col] = v;
        }
      }
    }
  }
}

DEVI void topk_attn_body(int b2, const float* __restrict__ tlin, float* __restrict__ outp){
  const int idx = b2 * 256 + threadIdx.x;
  if (idx >= 4 * 16 * 17 * 17) return;
  const int mm = idx % 17; int rest = idx / 17;
  const int nn = rest % 17; rest /= 17;
  const int h = rest % 16; const int b_ = rest / 16;
  const float* tq = tlin + ((size_t)(b_ * 17 + nn)) * 2048 + h * 64;
  const float* tk = tlin + ((size_t)(b_ * 17 + mm)) * 2048 + 1024 + h * 64;
  float s = 0.f;
  for (int d = 0; d < 64; d++) s += tq[d] * tk[d];
  outp[71303168 + idx] = s * 0.125f;
}

// one wave handles one 3072-col q_lin row: amax -> scale -> iq/ik int8 (first 2048 cols)
DEVI void qlin_quant_wave(int row, const u16* __restrict__ qlin,
                          float* __restrict__ s_ql, int8_t* __restrict__ iq, int8_t* __restrict__ ik){
  const int lane = threadIdx.x & 63;
  const u16* rp = qlin + (size_t)row * 3072;
  uint4 raw[6];
  float am = 0.f;
  for (int i = 0; i < 6; i++){
    raw[i] = *(const uint4*)(rp + i * 512 + lane * 8);
    const u16* pp = (const u16*)&raw[i];
    for (int j = 0; j < 8; j++) am = fmaxf(am, fabsf(ubf(pp[j])));
  }
  am = waveReduceMax(am);
  const float s = fmaxf(am, 1e-5f) / 127.0f;
  if (lane == 0) s_ql[row] = s;
  const int b_ = row >> 10, n = row & 1023;
  for (int i = 0; i < 4; i++){
    const int o0 = i * 512 + lane * 8;
    int8_t* dst = (o0 < 1024) ? iq : ik;
    const int oo = o0 & 1023, h = oo >> 6, d = oo & 63;
    const size_t base = (((size_t)(b_ * 16 + h) * 1024 + n) * 64 + d);
    const u16* pp = (const u16*)&raw[i];
    union { int8_t c[8]; unsigned long long u; } pk;
    for (int j = 0; j < 8; j++)
      pk.c[j] = (int8_t)(int)fminf(fmaxf(rintf(ubf(pp[j]) / s), -128.f), 127.f);
    *(unsigned long long*)(dst + base) = pk.u;
  }
}

DEVI void attn_body(u16* vt, int qt, int bz, const u16* __restrict__ qkv, u16* __restrict__ aout){
  const int t = threadIdx.x, l = t & 63, w = t >> 6, lr = l & 15, lg = l >> 4;
  const int b_ = bz >> 4, h = bz & 15;
  const u16* Q  = qkv + (size_t)bz * 65536;
  const u16* Kg = qkv + (size_t)(64 + bz) * 65536;
  const u16* Vg = qkv + (size_t)(128 + bz) * 65536;
  const int q0 = qt * 64 + w * 16;
  const bf16x8 bq0 = *(const bf16x8*)(Q + (size_t)(q0 + lr) * 64 + lg * 8);
  const bf16x8 bq1 = *(const bf16x8*)(Q + (size_t)(q0 + lr) * 64 + 32 + lg * 8);
  float m = -1e30f, lsum = 0.f;
  f32x4 o[4];
  f32x4 zf = {0.f, 0.f, 0.f, 0.f};
  for (int dt = 0; dt < 4; dt++) o[dt] = zf;
  const int hi = lg & 1, tt = lg >> 1;
  const int srcA = lr + 32 * hi, srcB = srcA + 16;
  const int vr = t >> 3, voff = (t & 7) * 8;
  {
    uint4 vv = *(const uint4*)(Vg + (size_t)vr * 64 + voff);
    const u16* pv = (const u16*)&vv;
    for (int j = 0; j < 8; j++) vt[(0 * 64 + voff + j) * 40 + vr] = pv[j];
  }
  __syncthreads();
  int cur = 0;
  for (int kv0 = 0; kv0 < 1024; kv0 += 32){
    const bf16x8 ak00 = *(const bf16x8*)(Kg + (size_t)(kv0 + lr) * 64 + lg * 8);
    const bf16x8 ak01 = *(const bf16x8*)(Kg + (size_t)(kv0 + lr) * 64 + 32 + lg * 8);
    const bf16x8 ak10 = *(const bf16x8*)(Kg + (size_t)(kv0 + 16 + lr) * 64 + lg * 8);
    const bf16x8 ak11 = *(const bf16x8*)(Kg + (size_t)(kv0 + 16 + lr) * 64 + 32 + lg * 8);
    const bool more = (kv0 + 32) < 1024;
    uint4 vn = {0, 0, 0, 0};
    if (more) vn = *(const uint4*)(Vg + (size_t)(kv0 + 32 + vr) * 64 + voff);
    f32x4 st[2];
    {
      __builtin_amdgcn_s_setprio(1);
      f32x4 c = zf;
      c = __builtin_amdgcn_mfma_f32_16x16x32_bf16(ak00, bq0, c, 0, 0, 0);
      c = __builtin_amdgcn_mfma_f32_16x16x32_bf16(ak01, bq1, c, 0, 0, 0);
      st[0] = c;
      c = zf;
      c = __builtin_amdgcn_mfma_f32_16x16x32_bf16(ak10, bq0, c, 0, 0, 0);
      c = __builtin_amdgcn_mfma_f32_16x16x32_bf16(ak11, bq1, c, 0, 0, 0);
      st[1] = c;
      __builtin_amdgcn_s_setprio(0);
    }
    float tmax = -1e30f;
    for (int kvt = 0; kvt < 2; kvt++)
      for (int r = 0; r < 4; r++){ st[kvt][r] *= 0.125f; tmax = fmaxf(tmax, st[kvt][r]); }
    tmax = fmaxf(tmax, __shfl_xor(tmax, 16));
    tmax = fmaxf(tmax, __shfl_xor(tmax, 32));
    const float mn = fmaxf(m, tmax);
    const float f = __expf(m - mn);
    m = mn;
    float p[2][4], psum = 0.f;
    for (int kvt = 0; kvt < 2; kvt++)
      for (int r = 0; r < 4; r++){ float e = __expf(st[kvt][r] - mn); p[kvt][r] = e; psum += e; }
    psum += __shfl_xor(psum, 16);
    psum += __shfl_xor(psum, 32);
    lsum = lsum * f + psum;
    for (int dt = 0; dt < 4; dt++) for (int r = 0; r < 4; r++) o[dt][r] *= f;
    int pk00 = (int)packbf(p[0][0], p[0][1]), pk01 = (int)packbf(p[0][2], p[0][3]);
    int pk10 = (int)packbf(p[1][0], p[1][1]), pk11 = (int)packbf(p[1][2], p[1][3]);
    int a0 = __shfl(pk00, srcA), a1 = __shfl(pk10, srcA);
    int b0 = __shfl(pk01, srcA), b1 = __shfl(pk11, srcA);
    int c0 = __shfl(pk00, srcB), c1 = __shfl(pk10, srcB);
    int d0 = __shfl(pk01, srcB), d1 = __shfl(pk11, srcB);
    union { unsigned u[4]; bf16x8 v; } bp;
    bp.u[0] = (unsigned)(tt ? a1 : a0);
    bp.u[1] = (unsigned)(tt ? b1 : b0);
    bp.u[2] = (unsigned)(tt ? c1 : c0);
    bp.u[3] = (unsigned)(tt ? d1 : d0);
    __builtin_amdgcn_s_setprio(1);
    for (int dt = 0; dt < 4; dt++){
      bf16x8 av = *(const bf16x8*)(&vt[(cur * 64 + dt * 16 + lr) * 40 + lg * 8]);
      o[dt] = __builtin_amdgcn_mfma_f32_16x16x32_bf16(av, bp.v, o[dt], 0, 0, 0);
    }
    __builtin_amdgcn_s_setprio(0);
    if (more){
      const u16* pv = (const u16*)&vn;
      for (int j = 0; j < 8; j++) vt[((cur ^ 1) * 64 + voff + j) * 40 + vr] = pv[j];
    }
    __syncthreads();
    cur ^= 1;
  }
  const float rn = 1.0f / lsum;
  for (int dt = 0; dt < 4; dt++){
    ushort4 hv;
    hv.x = bfu(o[dt][0] * rn); hv.y = bfu(o[dt][1] * rn);
    hv.z = bfu(o[dt][2] * rn); hv.w = bfu(o[dt][3] * rn);
    *(ushort4*)(aout + ((size_t)(b_ * 1024 + q0 + lr)) * 1024 + h * 64 + dt * 16 + lg * 4) = hv;
  }
}

DEVI void qattn_body(int b2, const int8_t* __restrict__ iq, const int8_t* __restrict__ ik,
    const float* __restrict__ s_ql, float* __restrict__ outp){
  const int t = threadIdx.x, l = t & 63, w = t >> 6, lr = l & 15, lg = l >> 4;
  const int n0 = (b2 & 7) * 128, m0 = ((b2 >> 3) & 7) * 128, bz = b2 >> 6;
  const int wm = (w >> 1) * 64, wn = (w & 1) * 64;
  const int b_ = bz >> 4;
  const int8_t* Aq = iq + (size_t)bz * 65536;
  const int8_t* Bk = ik + (size_t)bz * 65536;
  i32x4 a[4], b[4];
  for (int i = 0; i < 4; i++) a[i] = *(const i32x4*)(Aq + (size_t)(m0 + wm + i * 16 + lr) * 64 + lg * 16);
  for (int j = 0; j < 4; j++) b[j] = *(const i32x4*)(Bk + (size_t)(n0 + wn + j * 16 + lr) * 64 + lg * 16);
  float* op = outp + 4194304 + (size_t)bz * 1048576;
  i32x4 z = {0, 0, 0, 0};
  for (int i = 0; i < 4; i++){
    int row = m0 + wm + i * 16 + lg * 4;
    for (int j = 0; j < 4; j++){
      i32x4 acc = __builtin_amdgcn_mfma_i32_16x16x64_i8(a[i], b[j], z, 0, 0, 0);
      int col = n0 + wn + j * 16 + lr;
      float sc = s_ql[b_ * 1024 + col] * 0.125f;
      for (int r = 0; r < 4; r++)
        op[(size_t)(row + r) * 1024 + col] = (float)acc[r] * s_ql[b_ * 1024 + row + r] * sc;
    }
  }
}

// ---------------- stage kernels ----------------
// layout: [0,544) topk_lin | [544,1568) quant x | [1568,2336) quant W | [2336,2848) Wp cast | 2848 quant_b
__global__ __launch_bounds__(256) void stageA(
    const float* __restrict__ x, const float* __restrict__ Wq, const float* __restrict__ bq,
    const float* __restrict__ Wp,
    int8_t* __restrict__ ix, u16* __restrict__ xb, float* __restrict__ sx,
    int8_t* __restrict__ iw, u16* __restrict__ wb, float* __restrict__ sw,
    float* __restrict__ qbv, u16* __restrict__ Wpb, float* __restrict__ tlin){
  __shared__ float sred[4];
  const int bid = blockIdx.x, t = threadIdx.x, wv = t >> 6;
  if (bid < 544){
    topk_lin_body(bid * 256 + t, x, Wq, bq, tlin);
  } else if (bid < 1568){
    quant_row_wave(x, ix, xb, sx, (bid - 544) * 4 + wv);
  } else if (bid < 2336){
    quant_row_wave(Wq, iw, wb, sw, (bid - 1568) * 4 + wv);
  } else if (bid < 2848){
    const int i = ((bid - 2336) * 256 + t) * 8;
    float4 a = *(const float4*)(Wp + i);
    float4 b = *(const float4*)(Wp + i + 4);
    ushort4 h0; h0.x = bfu(a.x); h0.y = bfu(a.y); h0.z = bfu(a.z); h0.w = bfu(a.w);
    ushort4 h1; h1.x = bfu(b.x); h1.y = bfu(b.y); h1.z = bfu(b.z); h1.w = bfu(b.w);
    *(ushort4*)(Wpb + i) = h0;
    *(ushort4*)(Wpb + i + 4) = h1;
  } else {
    quant_b_body(bq, qbv, sred);
  }
}

// layout: [0,768) bf16 QKV tiles (longer blocks first) | [768,1536) i8 tiles
__global__ __launch_bounds__(256) void stageB(
    const int8_t* __restrict__ ix, const int8_t* __restrict__ iw, const float* __restrict__ sx,
    const float* __restrict__ sw, const float* __restrict__ qbv, u16* __restrict__ qlin,
    const u16* __restrict__ xb, const u16* __restrict__ wb, const float* __restrict__ bq,
    u16* __restrict__ qkv){
  __shared__ __align__(16) char smem[16384];
  const int bid = blockIdx.x;
  if (bid < 768){
    const int tid = (bid & 7) * 96 + (bid >> 3);           // XCD-chunked
    gemm_bf16_body<0>(smem, tid, xb, wb, bq, qkv, 1024, 3072, 24);
  } else {
    const int g = bid - 768;
    const int tid = (g & 7) * 96 + (g >> 3);
    gemm_i8_body(smem, tid, ix, iw, sx, sw, qbv, qlin);
  }
}

// layout: [0,1024) attn | [1024,2048) qlin_quant (wave-per-row) | [2048,2121) topk_attn
__global__ __launch_bounds__(256) void stageC(
    const u16* __restrict__ qkv, u16* __restrict__ aout,
    const u16* __restrict__ qlin, float* __restrict__ sql,
    int8_t* __restrict__ iq, int8_t* __restrict__ ik,
    const float* __restrict__ tlin, float* __restrict__ dout){
  __shared__ __align__(16) char smem[10240];
  const int bid = blockIdx.x, wv = threadIdx.x >> 6;
  if (bid < 1024){
    const int wk = (bid & 7) * 128 + (bid >> 3);           // 8 bz per XCD chunk
    attn_body((u16*)smem, wk & 15, wk >> 4, qkv, aout);
  } else if (bid < 2048){
    qlin_quant_wave((bid - 1024) * 4 + wv, qlin, sql, iq, ik);
  } else {
    topk_attn_body(bid - 2048, tlin, dout);
  }
}

__global__ __launch_bounds__(256) void stageD(
    const u16* __restrict__ aout, const u16* __restrict__ Wpb, const float* __restrict__ bp,
    float* __restrict__ dout,
    const int8_t* __restrict__ iq, const int8_t* __restrict__ ik, const float* __restrict__ sql){
  __shared__ __align__(16) char smem[16384];
  const int bid = blockIdx.x;
  if (bid < 256) gemm_bf16_body<1>(smem, bid, aout, Wpb, bp, dout, 1024, 1024, 8);
  else {
    const int g = bid - 256;
    const int w = (g & 7) * 512 + (g >> 3);                // 8 bz per XCD chunk
    qattn_body(w, iq, ik, sql, dout);
  }
}

// ---------------- launcher ----------------
extern "C" void kernel_launch(void* const* d_in, const int* in_sizes, int n_in,
                              void* d_out, int out_size, void* d_ws, size_t ws_size,
                              hipStream_t stream){
  const float* x  = (const float*)d_in[0];
  const float* Wq = (const float*)d_in[1];
  const float* bq = (const float*)d_in[2];
  const float* Wp = (const float*)d_in[3];
  const float* bp = (const float*)d_in[4];
  char* ws = (char*)d_ws;
  size_t off = 0;
  auto alloc = [&](size_t bytes) -> void* {
    void* p = ws + off; off += (bytes + 255) & ~(size_t)255; return p;
  };
  u16*    qlin = (u16*)   alloc(4096ull * 3072 * 2);   // bf16
  int8_t* ix   = (int8_t*)alloc(4096ull * 1024);
  int8_t* iw   = (int8_t*)alloc(3072ull * 1024);
  int8_t* iq   = (int8_t*)alloc(64ull * 1024 * 64);
  int8_t* ik   = (int8_t*)alloc(64ull * 1024 * 64);
  u16*    xb   = (u16*)   alloc(4096ull * 1024 * 2);
  u16*    Wb   = (u16*)   alloc(3072ull * 1024 * 2);
  u16*    qkv  = (u16*)   alloc(3ull * 64 * 1024 * 64 * 2);
  u16*    aout = (u16*)   alloc(4096ull * 1024 * 2);
  u16*    Wpb  = (u16*)   alloc(1024ull * 1024 * 2);
  float*  tlin = (float*) alloc(4ull * 17 * 2048 * 4);
  float*  sx   = (float*) alloc(4096 * 4);
  float*  sw   = (float*) alloc(3072 * 4);
  float*  qbv  = (float*) alloc(3072 * 4);
  float*  sql  = (float*) alloc(4096 * 4);
  float*  dout = (float*)d_out;

  stageA<<<2849, 256, 0, stream>>>(x, Wq, bq, Wp, ix, xb, sx, iw, Wb, sw, qbv, Wpb, tlin);
  stageB<<<1536, 256, 0, stream>>>(ix, iw, sx, sw, qbv, qlin, xb, Wb, bq, qkv);
  stageC<<<2121, 256, 0, stream>>>(qkv, aout, qlin, sql, iq, ik, tlin, dout);
  stageD<<<4352, 256, 0, stream>>>(aout, Wpb, bp, dout, iq, ik, sql);
}

// Round 11
// 239.433 us; speedup vs baseline: 1.0618x; 1.0091x over previous
//
#include <hip/hip_runtime.h>
#include <stdint.h>

typedef __bf16 bf16x8 __attribute__((ext_vector_type(8)));
typedef float f32x4 __attribute__((ext_vector_type(4)));
typedef int i32x4 __attribute__((ext_vector_type(4)));
typedef unsigned short u16;

#define DEVI static __device__ __forceinline__

// f32 -> bf16 (RNE)
DEVI u16 bfu(float f){
  unsigned u = __builtin_bit_cast(unsigned, f);
  unsigned r = u + 0x7fffu + ((u >> 16) & 1u);
  return (u16)(r >> 16);
}
DEVI float ubf(u16 h){
  unsigned u = ((unsigned)h) << 16;
  return __builtin_bit_cast(float, u);
}
DEVI unsigned packbf(float a, float b){
  return (unsigned)bfu(a) | ((unsigned)bfu(b) << 16);
}

// async global->LDS, 16B/lane; LDS dest = wave-uniform base + lane*16
DEVI void gload16(const void* g, void* s){
  __builtin_amdgcn_global_load_lds(
      (const __attribute__((address_space(1))) unsigned int*)g,
      (__attribute__((address_space(3))) unsigned int*)s, 16, 0, 0);
}

DEVI float waveReduceMax(float v){
  for (int off = 1; off < 64; off <<= 1) v = fmaxf(v, __shfl_xor(v, off));
  return v;
}

DEVI float blockReduceMax(float v, float* sred){
  for (int off = 32; off; off >>= 1) v = fmaxf(v, __shfl_xor(v, off));
  int w = threadIdx.x >> 6;
  if ((threadIdx.x & 63) == 0) sred[w] = v;
  __syncthreads();
  float r = fmaxf(fmaxf(sred[0], sred[1]), fmaxf(sred[2], sred[3]));
  __syncthreads();
  return r;
}

// ---------------- bodies ----------------
// one wave handles one 1024-row: amax -> scale -> int8 + bf16 copies. No LDS/barriers.
DEVI void quant_row_wave(const float* __restrict__ in, int8_t* __restrict__ qo,
                         u16* __restrict__ bo, float* __restrict__ so, int row){
  const int lane = threadIdx.x & 63;
  const float* rp = in + (size_t)row * 1024;
  float4 v[4];
  float am = 0.f;
  for (int i = 0; i < 4; i++){
    v[i] = *(const float4*)(rp + i * 256 + lane * 4);
    am = fmaxf(am, fmaxf(fmaxf(fabsf(v[i].x), fabsf(v[i].y)),
                         fmaxf(fabsf(v[i].z), fabsf(v[i].w))));
  }
  am = waveReduceMax(am);
  const float s = fmaxf(am, 1e-5f) / 127.0f;
  if (lane == 0) so[row] = s;
  for (int i = 0; i < 4; i++){
    char4 q;
    q.x = (int8_t)(int)fminf(fmaxf(rintf(v[i].x / s), -128.f), 127.f);
    q.y = (int8_t)(int)fminf(fmaxf(rintf(v[i].y / s), -128.f), 127.f);
    q.z = (int8_t)(int)fminf(fmaxf(rintf(v[i].z / s), -128.f), 127.f);
    q.w = (int8_t)(int)fminf(fmaxf(rintf(v[i].w / s), -128.f), 127.f);
    *(char4*)(qo + (size_t)row * 1024 + i * 256 + lane * 4) = q;
    ushort4 h; h.x = bfu(v[i].x); h.y = bfu(v[i].y); h.z = bfu(v[i].z); h.w = bfu(v[i].w);
    *(ushort4*)(bo + (size_t)row * 1024 + i * 256 + lane * 4) = h;
  }
}

DEVI void quant_b_body(const float* __restrict__ b, float* __restrict__ qb, float* sred){
  const int t = threadIdx.x;
  float am = 0.f;
  for (int i = t; i < 3072; i += 256) am = fmaxf(am, fabsf(b[i]));
  am = blockReduceMax(am, sred);
  const float s = fmaxf(am, 1e-5f) / 127.0f;
  for (int i = t; i < 3072; i += 256){
    float q = fminf(fmaxf(rintf(b[i] / s), -128.f), 127.f);
    qb[i] = q * s;
  }
}

DEVI void topk_lin_body(int idx, const float* __restrict__ x, const float* __restrict__ Wq,
                        const float* __restrict__ bq, float* __restrict__ tlin){
  const int o = idx & 2047, bn = idx >> 11;
  const int b_ = bn / 17, n = bn % 17;
  const float* xr = x + ((size_t)b_ * 1024 + n) * 1024;
  const float* wr = Wq + (size_t)o * 1024;
  const float4* x4 = (const float4*)xr;
  const float4* w4 = (const float4*)wr;
  float s = 0.f;
  for (int c = 0; c < 64; c++){
    float4 a = x4[c], b = w4[c];
    s += a.x * b.x + a.y * b.y + a.z * b.z + a.w * b.w;
  }
  s += xr[256] * wr[256];
  tlin[idx] = s + bq[o];
}

// i8 GEMM, BK=64, linear LDS, bf16 output
DEVI void gemm_i8_body(char* smem, int tid, const int8_t* __restrict__ A, const int8_t* __restrict__ Bm,
    const float* __restrict__ sx, const float* __restrict__ sw, const float* __restrict__ qb,
    u16* __restrict__ out){
  int8_t* As = (int8_t*)smem;
  int8_t* Bs = (int8_t*)(smem + 8192);
  const int t = threadIdx.x, l = t & 63, w = t >> 6;
  const int m0 = (tid / 24) * 128, n0 = (tid % 24) * 128;
  const int wm = (w >> 1) * 64, wn = (w & 1) * 64, lr = l & 15, lg = l >> 4;
  i32x4 acc[4][4];
  i32x4 z = {0, 0, 0, 0};
  for (int i = 0; i < 4; i++) for (int j = 0; j < 4; j++) acc[i][j] = z;
  for (int kt = 0; kt < 16; kt++){
    __syncthreads();
    for (int it = 0; it < 2; it++){
      int c = w * 2 + it;
      int idx = c * 64 + l;
      int r = idx >> 2, boff = (idx & 3) * 16;
      gload16(A  + (size_t)(m0 + r) * 1024 + kt * 64 + boff, &As[c * 1024]);
      gload16(Bm + (size_t)(n0 + r) * 1024 + kt * 64 + boff, &Bs[c * 1024]);
    }
    __syncthreads();
    i32x4 a[4], b[4];
    for (int i = 0; i < 4; i++) a[i] = *(const i32x4*)(&As[(wm + i * 16 + lr) * 64 + lg * 16]);
    for (int j = 0; j < 4; j++) b[j] = *(const i32x4*)(&Bs[(wn + j * 16 + lr) * 64 + lg * 16]);
    __builtin_amdgcn_s_setprio(1);
    for (int i = 0; i < 4; i++)
      for (int j = 0; j < 4; j++)
        acc[i][j] = __builtin_amdgcn_mfma_i32_16x16x64_i8(a[i], b[j], acc[i][j], 0, 0, 0);
    __builtin_amdgcn_s_setprio(0);
  }
  for (int i = 0; i < 4; i++){
    int row = m0 + wm + i * 16 + lg * 4;
    for (int j = 0; j < 4; j++){
      int col = n0 + wn + j * 16 + lr;
      float swc = sw[col], qbc = qb[col];
      for (int r = 0; r < 4; r++)
        out[(size_t)(row + r) * 3072 + col] = bfu((float)acc[i][j][r] * sx[row + r] * swc + qbc);
    }
  }
}

// bf16 GEMM, BK=32, linear LDS. MODE 0: QKV scatter+bias; MODE 1: proj f32 out
template<int MODE>
DEVI void gemm_bf16_body(char* smem, int tid, const u16* __restrict__ A, const u16* __restrict__ Bm,
    const float* __restrict__ bias, void* __restrict__ outp, int K, int N, int nxb){
  u16* As = (u16*)smem;
  u16* Bs = (u16*)(smem + 8192);
  const int t = threadIdx.x, l = t & 63, w = t >> 6;
  const int m0 = (tid / nxb) * 128, n0 = (tid % nxb) * 128;
  const int wm = (w >> 1) * 64, wn = (w & 1) * 64, lr = l & 15, lg = l >> 4;
  f32x4 acc[4][4];
  f32x4 z = {0.f, 0.f, 0.f, 0.f};
  for (int i = 0; i < 4; i++) for (int j = 0; j < 4; j++) acc[i][j] = z;
  const int nkt = K >> 5;
  for (int kt = 0; kt < nkt; kt++){
    __syncthreads();
    for (int it = 0; it < 2; it++){
      int c = w * 2 + it;
      int idx = c * 64 + l;
      int r = idx >> 2, off = (idx & 3) * 8;
      gload16(A  + (size_t)(m0 + r) * K + kt * 32 + off, &As[c * 512]);
      gload16(Bm + (size_t)(n0 + r) * K + kt * 32 + off, &Bs[c * 512]);
    }
    __syncthreads();
    bf16x8 a[4], b[4];
    for (int i = 0; i < 4; i++) a[i] = *(const bf16x8*)(&As[(wm + i * 16 + lr) * 32 + lg * 8]);
    for (int j = 0; j < 4; j++) b[j] = *(const bf16x8*)(&Bs[(wn + j * 16 + lr) * 32 + lg * 8]);
    __builtin_amdgcn_s_setprio(1);
    for (int i = 0; i < 4; i++)
      for (int j = 0; j < 4; j++)
        acc[i][j] = __builtin_amdgcn_mfma_f32_16x16x32_bf16(a[i], b[j], acc[i][j], 0, 0, 0);
    __builtin_amdgcn_s_setprio(0);
  }
  for (int i = 0; i < 4; i++){
    int row = m0 + wm + i * 16 + lg * 4;
    for (int j = 0; j < 4; j++){
      int col = n0 + wn + j * 16 + lr;
      float bc = bias[col];
      for (int r = 0; r < 4; r++){
        float v = acc[i][j][r] + bc;
        if (MODE == 0){
          int s = col >> 10, h = (col >> 6) & 15, d = col & 63;
          int b_ = (row + r) >> 10, n = (row + r) & 1023;
          ((u16*)outp)[(((size_t)(s * 64 + b_ * 16 + h)) * 1024 + n) * 64 + d] = bfu(v);
        } else {
          ((float*)outp)[(size_t)(row + r) * N + col] = v;
        }
      }
    }
  }
}

DEVI void topk_attn_body(int b2, const float* __restrict__ tlin, float* __restrict__ outp){
  const int idx = b2 * 256 + threadIdx.x;
  if (idx >= 4 * 16 * 17 * 17) return;
  const int mm = idx % 17; int rest = idx / 17;
  const int nn = rest % 17; rest /= 17;
  const int h = rest % 16; const int b_ = rest / 16;
  const float* tq = tlin + ((size_t)(b_ * 17 + nn)) * 2048 + h * 64;
  const float* tk = tlin + ((size_t)(b_ * 17 + mm)) * 2048 + 1024 + h * 64;
  float s = 0.f;
  for (int d = 0; d < 64; d++) s += tq[d] * tk[d];
  outp[71303168 + idx] = s * 0.125f;
}

// one wave handles one 3072-col q_lin row: amax -> scale -> iq/ik int8 (first 2048 cols)
DEVI void qlin_quant_wave(int row, const u16* __restrict__ qlin,
                          float* __restrict__ s_ql, int8_t* __restrict__ iq, int8_t* __restrict__ ik){
  const int lane = threadIdx.x & 63;
  const u16* rp = qlin + (size_t)row * 3072;
  uint4 raw[6];
  float am = 0.f;
  for (int i = 0; i < 6; i++){
    raw[i] = *(const uint4*)(rp + i * 512 + lane * 8);
    const u16* pp = (const u16*)&raw[i];
    for (int j = 0; j < 8; j++) am = fmaxf(am, fabsf(ubf(pp[j])));
  }
  am = waveReduceMax(am);
  const float s = fmaxf(am, 1e-5f) / 127.0f;
  if (lane == 0) s_ql[row] = s;
  const int b_ = row >> 10, n = row & 1023;
  for (int i = 0; i < 4; i++){
    const int o0 = i * 512 + lane * 8;
    int8_t* dst = (o0 < 1024) ? iq : ik;
    const int oo = o0 & 1023, h = oo >> 6, d = oo & 63;
    const size_t base = (((size_t)(b_ * 16 + h) * 1024 + n) * 64 + d);
    const u16* pp = (const u16*)&raw[i];
    union { int8_t c[8]; unsigned long long u; } pk;
    for (int j = 0; j < 8; j++)
      pk.c[j] = (int8_t)(int)fminf(fmaxf(rintf(ubf(pp[j]) / s), -128.f), 127.f);
    *(unsigned long long*)(dst + base) = pk.u;
  }
}

DEVI void attn_body(u16* vt, int qt, int bz, const u16* __restrict__ qkv, u16* __restrict__ aout){
  const int t = threadIdx.x, l = t & 63, w = t >> 6, lr = l & 15, lg = l >> 4;
  const int b_ = bz >> 4, h = bz & 15;
  const u16* Q  = qkv + (size_t)bz * 65536;
  const u16* Kg = qkv + (size_t)(64 + bz) * 65536;
  const u16* Vg = qkv + (size_t)(128 + bz) * 65536;
  const int q0 = qt * 64 + w * 16;
  const bf16x8 bq0 = *(const bf16x8*)(Q + (size_t)(q0 + lr) * 64 + lg * 8);
  const bf16x8 bq1 = *(const bf16x8*)(Q + (size_t)(q0 + lr) * 64 + 32 + lg * 8);
  float m = -1e30f, lsum = 0.f;
  f32x4 o[4];
  f32x4 zf = {0.f, 0.f, 0.f, 0.f};
  for (int dt = 0; dt < 4; dt++) o[dt] = zf;
  const int hi = lg & 1, tt = lg >> 1;
  const int srcA = lr + 32 * hi, srcB = srcA + 16;
  const int vr = t >> 3, voff = (t & 7) * 8;
  {
    uint4 vv = *(const uint4*)(Vg + (size_t)vr * 64 + voff);
    const u16* pv = (const u16*)&vv;
    for (int j = 0; j < 8; j++) vt[(0 * 64 + voff + j) * 40 + vr] = pv[j];
  }
  __syncthreads();
  int cur = 0;
  for (int kv0 = 0; kv0 < 1024; kv0 += 32){
    const bf16x8 ak00 = *(const bf16x8*)(Kg + (size_t)(kv0 + lr) * 64 + lg * 8);
    const bf16x8 ak01 = *(const bf16x8*)(Kg + (size_t)(kv0 + lr) * 64 + 32 + lg * 8);
    const bf16x8 ak10 = *(const bf16x8*)(Kg + (size_t)(kv0 + 16 + lr) * 64 + lg * 8);
    const bf16x8 ak11 = *(const bf16x8*)(Kg + (size_t)(kv0 + 16 + lr) * 64 + 32 + lg * 8);
    const bool more = (kv0 + 32) < 1024;
    uint4 vn = {0, 0, 0, 0};
    if (more) vn = *(const uint4*)(Vg + (size_t)(kv0 + 32 + vr) * 64 + voff);
    f32x4 st[2];
    {
      __builtin_amdgcn_s_setprio(1);
      f32x4 c = zf;
      c = __builtin_amdgcn_mfma_f32_16x16x32_bf16(ak00, bq0, c, 0, 0, 0);
      c = __builtin_amdgcn_mfma_f32_16x16x32_bf16(ak01, bq1, c, 0, 0, 0);
      st[0] = c;
      c = zf;
      c = __builtin_amdgcn_mfma_f32_16x16x32_bf16(ak10, bq0, c, 0, 0, 0);
      c = __builtin_amdgcn_mfma_f32_16x16x32_bf16(ak11, bq1, c, 0, 0, 0);
      st[1] = c;
      __builtin_amdgcn_s_setprio(0);
    }
    float tmax = -1e30f;
    for (int kvt = 0; kvt < 2; kvt++)
      for (int r = 0; r < 4; r++){ st[kvt][r] *= 0.125f; tmax = fmaxf(tmax, st[kvt][r]); }
    tmax = fmaxf(tmax, __shfl_xor(tmax, 16));
    tmax = fmaxf(tmax, __shfl_xor(tmax, 32));
    const float mn = fmaxf(m, tmax);
    const float f = __expf(m - mn);
    m = mn;
    float p[2][4], psum = 0.f;
    for (int kvt = 0; kvt < 2; kvt++)
      for (int r = 0; r < 4; r++){ float e = __expf(st[kvt][r] - mn); p[kvt][r] = e; psum += e; }
    psum += __shfl_xor(psum, 16);
    psum += __shfl_xor(psum, 32);
    lsum = lsum * f + psum;
    for (int dt = 0; dt < 4; dt++) for (int r = 0; r < 4; r++) o[dt][r] *= f;
    int pk00 = (int)packbf(p[0][0], p[0][1]), pk01 = (int)packbf(p[0][2], p[0][3]);
    int pk10 = (int)packbf(p[1][0], p[1][1]), pk11 = (int)packbf(p[1][2], p[1][3]);
    int a0 = __shfl(pk00, srcA), a1 = __shfl(pk10, srcA);
    int b0 = __shfl(pk01, srcA), b1 = __shfl(pk11, srcA);
    int c0 = __shfl(pk00, srcB), c1 = __shfl(pk10, srcB);
    int d0 = __shfl(pk01, srcB), d1 = __shfl(pk11, srcB);
    union { unsigned u[4]; bf16x8 v; } bp;
    bp.u[0] = (unsigned)(tt ? a1 : a0);
    bp.u[1] = (unsigned)(tt ? b1 : b0);
    bp.u[2] = (unsigned)(tt ? c1 : c0);
    bp.u[3] = (unsigned)(tt ? d1 : d0);
    __builtin_amdgcn_s_setprio(1);
    for (int dt = 0; dt < 4; dt++){
      bf16x8 av = *(const bf16x8*)(&vt[(cur * 64 + dt * 16 + lr) * 40 + lg * 8]);
      o[dt] = __builtin_amdgcn_mfma_f32_16x16x32_bf16(av, bp.v, o[dt], 0, 0, 0);
    }
    __builtin_amdgcn_s_setprio(0);
    if (more){
      const u16* pv = (const u16*)&vn;
      for (int j = 0; j < 8; j++) vt[((cur ^ 1) * 64 + voff + j) * 40 + vr] = pv[j];
    }
    __syncthreads();
    cur ^= 1;
  }
  const float rn = 1.0f / lsum;
  for (int dt = 0; dt < 4; dt++){
    ushort4 hv;
    hv.x = bfu(o[dt][0] * rn); hv.y = bfu(o[dt][1] * rn);
    hv.z = bfu(o[dt][2] * rn); hv.w = bfu(o[dt][3] * rn);
    *(ushort4*)(aout + ((size_t)(b_ * 1024 + q0 + lr)) * 1024 + h * 64 + dt * 16 + lg * 4) = hv;
  }
}

DEVI void qattn_body(int b2, const int8_t* __restrict__ iq, const int8_t* __restrict__ ik,
    const float* __restrict__ s_ql, float* __restrict__ outp){
  const int t = threadIdx.x, l = t & 63, w = t >> 6, lr = l & 15, lg = l >> 4;
  const int n0 = (b2 & 7) * 128, m0 = ((b2 >> 3) & 7) * 128, bz = b2 >> 6;
  const int wm = (w >> 1) * 64, wn = (w & 1) * 64;
  const int b_ = bz >> 4;
  const int8_t* Aq = iq + (size_t)bz * 65536;
  const int8_t* Bk = ik + (size_t)bz * 65536;
  i32x4 a[4], b[4];
  for (int i = 0; i < 4; i++) a[i] = *(const i32x4*)(Aq + (size_t)(m0 + wm + i * 16 + lr) * 64 + lg * 16);
  for (int j = 0; j < 4; j++) b[j] = *(const i32x4*)(Bk + (size_t)(n0 + wn + j * 16 + lr) * 64 + lg * 16);
  float* op = outp + 4194304 + (size_t)bz * 1048576;
  i32x4 z = {0, 0, 0, 0};
  for (int i = 0; i < 4; i++){
    int row = m0 + wm + i * 16 + lg * 4;
    for (int j = 0; j < 4; j++){
      i32x4 acc = __builtin_amdgcn_mfma_i32_16x16x64_i8(a[i], b[j], z, 0, 0, 0);
      int col = n0 + wn + j * 16 + lr;
      float sc = s_ql[b_ * 1024 + col] * 0.125f;
      for (int r = 0; r < 4; r++)
        op[(size_t)(row + r) * 1024 + col] = (float)acc[r] * s_ql[b_ * 1024 + row + r] * sc;
    }
  }
}

// ---------------- stage kernels ----------------
// layout: [0,544) topk_lin | [544,1568) quant x | [1568,2336) quant W | [2336,2848) Wp cast | 2848 quant_b
__global__ __launch_bounds__(256) void stageA(
    const float* __restrict__ x, const float* __restrict__ Wq, const float* __restrict__ bq,
    const float* __restrict__ Wp,
    int8_t* __restrict__ ix, u16* __restrict__ xb, float* __restrict__ sx,
    int8_t* __restrict__ iw, u16* __restrict__ wb, float* __restrict__ sw,
    float* __restrict__ qbv, u16* __restrict__ Wpb, float* __restrict__ tlin){
  __shared__ float sred[4];
  const int bid = blockIdx.x, t = threadIdx.x, wv = t >> 6;
  if (bid < 544){
    topk_lin_body(bid * 256 + t, x, Wq, bq, tlin);
  } else if (bid < 1568){
    quant_row_wave(x, ix, xb, sx, (bid - 544) * 4 + wv);
  } else if (bid < 2336){
    quant_row_wave(Wq, iw, wb, sw, (bid - 1568) * 4 + wv);
  } else if (bid < 2848){
    const int i = ((bid - 2336) * 256 + t) * 8;
    float4 a = *(const float4*)(Wp + i);
    float4 b = *(const float4*)(Wp + i + 4);
    ushort4 h0; h0.x = bfu(a.x); h0.y = bfu(a.y); h0.z = bfu(a.z); h0.w = bfu(a.w);
    ushort4 h1; h1.x = bfu(b.x); h1.y = bfu(b.y); h1.z = bfu(b.z); h1.w = bfu(b.w);
    *(ushort4*)(Wpb + i) = h0;
    *(ushort4*)(Wpb + i + 4) = h1;
  } else {
    quant_b_body(bq, qbv, sred);
  }
}

// layout: [0,768) bf16 QKV tiles (longer blocks first) | [768,1536) i8 tiles
// XCD regions reshaped 4m x 24n -> 8m x 12n: L2 footprint bf16 7MB->5MB, i8 3.5MB->2.5MB (fits)
__global__ __launch_bounds__(256) void stageB(
    const int8_t* __restrict__ ix, const int8_t* __restrict__ iw, const float* __restrict__ sx,
    const float* __restrict__ sw, const float* __restrict__ qbv, u16* __restrict__ qlin,
    const u16* __restrict__ xb, const u16* __restrict__ wb, const float* __restrict__ bq,
    u16* __restrict__ qkv){
  __shared__ __align__(16) char smem[16384];
  const int bid = blockIdx.x;
  if (bid < 768){
    const int xcd = bid & 7, seq = bid >> 3;               // 96 tiles per XCD
    const int rm = xcd >> 1, rn = xcd & 1;                 // 4x2 grid of 8m x 12n regions
    const int lm = seq / 12, ln = seq % 12;
    const int tid = (rm * 8 + lm) * 24 + (rn * 12 + ln);
    gemm_bf16_body<0>(smem, tid, xb, wb, bq, qkv, 1024, 3072, 24);
  } else {
    const int g = bid - 768;
    const int xcd = g & 7, seq = g >> 3;
    const int rm = xcd >> 1, rn = xcd & 1;
    const int lm = seq / 12, ln = seq % 12;
    const int tid = (rm * 8 + lm) * 24 + (rn * 12 + ln);
    gemm_i8_body(smem, tid, ix, iw, sx, sw, qbv, qlin);
  }
}

// layout: [0,1024) attn | [1024,2048) qlin_quant (wave-per-row) | [2048,2121) topk_attn
__global__ __launch_bounds__(256) void stageC(
    const u16* __restrict__ qkv, u16* __restrict__ aout,
    const u16* __restrict__ qlin, float* __restrict__ sql,
    int8_t* __restrict__ iq, int8_t* __restrict__ ik,
    const float* __restrict__ tlin, float* __restrict__ dout){
  __shared__ __align__(16) char smem[10240];
  const int bid = blockIdx.x, wv = threadIdx.x >> 6;
  if (bid < 1024){
    const int wk = (bid & 7) * 128 + (bid >> 3);           // 8 bz per XCD chunk
    attn_body((u16*)smem, wk & 15, wk >> 4, qkv, aout);
  } else if (bid < 2048){
    qlin_quant_wave((bid - 1024) * 4 + wv, qlin, sql, iq, ik);
  } else {
    topk_attn_body(bid - 2048, tlin, dout);
  }
}

__global__ __launch_bounds__(256) void stageD(
    const u16* __restrict__ aout, const u16* __restrict__ Wpb, const float* __restrict__ bp,
    float* __restrict__ dout,
    const int8_t* __restrict__ iq, const int8_t* __restrict__ ik, const float* __restrict__ sql){
  __shared__ __align__(16) char smem[16384];
  const int bid = blockIdx.x;
  if (bid < 256) gemm_bf16_body<1>(smem, bid, aout, Wpb, bp, dout, 1024, 1024, 8);
  else {
    const int g = bid - 256;
    const int w = (g & 7) * 512 + (g >> 3);                // 8 bz per XCD chunk
    qattn_body(w, iq, ik, sql, dout);
  }
}

// ---------------- launcher ----------------
extern "C" void kernel_launch(void* const* d_in, const int* in_sizes, int n_in,
                              void* d_out, int out_size, void* d_ws, size_t ws_size,
                              hipStream_t stream){
  const float* x  = (const float*)d_in[0];
  const float* Wq = (const float*)d_in[1];
  const float* bq = (const float*)d_in[2];
  const float* Wp = (const float*)d_in[3];
  const float* bp = (const float*)d_in[4];
  char* ws = (char*)d_ws;
  size_t off = 0;
  auto alloc = [&](size_t bytes) -> void* {
    void* p = ws + off; off += (bytes + 255) & ~(size_t)255; return p;
  };
  u16*    qlin = (u16*)   alloc(4096ull * 3072 * 2);   // bf16
  int8_t* ix   = (int8_t*)alloc(4096ull * 1024);
  int8_t* iw   = (int8_t*)alloc(3072ull * 1024);
  int8_t* iq   = (int8_t*)alloc(64ull * 1024 * 64);
  int8_t* ik   = (int8_t*)alloc(64ull * 1024 * 64);
  u16*    xb   = (u16*)   alloc(4096ull * 1024 * 2);
  u16*    Wb   = (u16*)   alloc(3072ull * 1024 * 2);
  u16*    qkv  = (u16*)   alloc(3ull * 64 * 1024 * 64 * 2);
  u16*    aout = (u16*)   alloc(4096ull * 1024 * 2);
  u16*    Wpb  = (u16*)   alloc(1024ull * 1024 * 2);
  float*  tlin = (float*) alloc(4ull * 17 * 2048 * 4);
  float*  sx   = (float*) alloc(4096 * 4);
  float*  sw   = (float*) alloc(3072 * 4);
  float*  qbv  = (float*) alloc(3072 * 4);
  float*  sql  = (float*) alloc(4096 * 4);
  float*  dout = (float*)d_out;

  stageA<<<2849, 256, 0, stream>>>(x, Wq, bq, Wp, ix, xb, sx, iw, Wb, sw, qbv, Wpb, tlin);
  stageB<<<1536, 256, 0, stream>>>(ix, iw, sx, sw, qbv, qlin, xb, Wb, bq, qkv);
  stageC<<<2121, 256, 0, stream>>>(qkv, aout, qlin, sql, iq, ik, tlin, dout);
  stageD<<<4352, 256, 0, stream>>>(aout, Wpb, bp, dout, iq, ik, sql);
}